// Round 6
// baseline (375.419 us; speedup 1.0000x reference)
//
#include <hip/hip_runtime.h>

// SSIM loss, streaming-row kernel, no LDS in the hot loop, no barriers.
// r5-r9: four source rewrites -> bit-identical counters (VGPR=64, WRITE
// ~28MB, VALU 65%, 203us). Model fitted to ALL rounds: the allocator
// honors the unified VGPR budget but splits it ~half arch / half accum
// (r0: budget 256 -> arch 112; r5-r9: budget 128 -> arch 64 exactly).
// With arch=64 the 55-float ring lives in AGPRs -> v_accvgpr ping-pong
// (+110 VALU/phase; predicted 117us issue vs measured 132us) and the
// overflow spills to scratch (28MB HBM residue). Source form is irrelevant;
// the budget split is the binding constraint.
// r10: waves_per_eu(2,2) -> budget 256 -> arch half ~128 >= ~105-reg
// working set. Ring stays arch, no ping-pong, no scratch. Occupancy drops
// to 2 waves/EU (25%) by design; clean issue time ~71us should win.
// Algorithm unchanged from r9 (absmax 0.0 r5-r9): per-lane 12-tap
// parity-shifted Gaussian (zero pad tap, fmaf(0,x,h)==h bit-exact),
// aligned float2 loads consumed immediately, 11-slot rolling accumulators.

#define IMG 512
#define OUT_DIM 502    // 512 - 10 (VALID conv twice)
#define WIN 11
#define BH 32          // output rows per band
#define NPHASE (BH + WIN - 1)   // 42
#define NPLANES 96

#define GAUSS_INIT {0.00102838f, 0.00759875f, 0.03600077f, 0.10936071f, \
                    0.21300553f, 0.26601172f, 0.21300553f, 0.10936071f, \
                    0.03600077f, 0.00759875f, 0.00102838f}

template<int PH>
__device__ __forceinline__ void phase_step(
    int base, int r0, int c, int cbase,
    const float* __restrict__ Xp, const float* __restrict__ Yp,
    float w0, float w1, float w2, float w3, float w4, float w5,
    float w6, float w7, float w8, float w9, float w10, float w11,
    float (&a)[5][WIN], float& local) {
    constexpr float G[WIN] = GAUSS_INIT;   // matches numpy fp32 (absmax 0.0)
    const int p = base + PH;
    if (p >= NPHASE) return;               // uniform; only last outer iter
    const int rr = min(r0 + p, IMG - 1);   // clamped rows feed only discarded outputs
    const float* px = Xp + rr * IMG + cbase;
    const float* py = Yp + rr * IMG + cbase;

    // Horizontal blur, 12 taps, parity-shifted weights. Each float2 pair is
    // consumed immediately after its load so the raw values die fast; tap
    // order stays ascending-k with 5 maps per tap -> bit-identical results.
    float h0 = 0.f, h1 = 0.f, h2 = 0.f, h3 = 0.f, h4 = 0.f;
#define PAIR(i, ka, kb) do {                                      \
        const float2 xv = *(const float2*)(px + 2 * (i));         \
        const float2 yv = *(const float2*)(py + 2 * (i));         \
        h0 = fmaf(w##ka, xv.x, h0);                               \
        h1 = fmaf(w##ka, yv.x, h1);                               \
        h2 = fmaf(w##ka, xv.x * xv.x, h2);                        \
        h3 = fmaf(w##ka, yv.x * yv.x, h3);                        \
        h4 = fmaf(w##ka, xv.x * yv.x, h4);                        \
        h0 = fmaf(w##kb, xv.y, h0);                               \
        h1 = fmaf(w##kb, yv.y, h1);                               \
        h2 = fmaf(w##kb, xv.y * xv.y, h2);                        \
        h3 = fmaf(w##kb, yv.y * yv.y, h3);                        \
        h4 = fmaf(w##kb, xv.y * yv.y, h4);                        \
    } while (0)
    PAIR(0, 0, 1); PAIR(1, 2, 3); PAIR(2, 4, 5);
    PAIR(3, 6, 7); PAIR(4, 8, 9); PAIR(5, 10, 11);
#undef PAIR

    // Row r contributes weight G[d] to output row r-d; slot (p-d) mod 11.
    // d==0 ASSIGNS its slot (freed by last phase's emit) -> no init/reset.
    // Every index is a true constexpr (template PH + literal d).
#define ACC(d) do {                                               \
        constexpr int s = (PH - (d) + 2 * WIN) % WIN;             \
        constexpr float g = G[(d)];                               \
        if ((d) == 0) {                                           \
            a[0][s] = g * h0; a[1][s] = g * h1; a[2][s] = g * h2; \
            a[3][s] = g * h3; a[4][s] = g * h4;                   \
        } else {                                                  \
            a[0][s] = fmaf(g, h0, a[0][s]);                       \
            a[1][s] = fmaf(g, h1, a[1][s]);                       \
            a[2][s] = fmaf(g, h2, a[2][s]);                       \
            a[3][s] = fmaf(g, h3, a[3][s]);                       \
            a[4][s] = fmaf(g, h4, a[4][s]);                       \
        }                                                         \
    } while (0)
    ACC(0); ACC(1); ACC(2); ACC(3); ACC(4); ACC(5);
    ACC(6); ACC(7); ACC(8); ACC(9); ACC(10);
#undef ACC

    // Output row o = r-10 completed this phase; its slot is (PH+1)%11.
    if (p >= WIN - 1) {
        const int o = r0 + p - (WIN - 1);
        if (o < OUT_DIM && c < OUT_DIM) {
            constexpr int se = (PH + 1) % WIN;
            const float C1 = 0.0001f, C2 = 0.0009f;
            const float m1 = a[0][se], m2 = a[1][se];
            const float m1sq = m1 * m1, m2sq = m2 * m2, m12 = m1 * m2;
            const float s1  = a[2][se] - m1sq;
            const float s2  = a[3][se] - m2sq;
            const float s12 = a[4][se] - m12;
            const float num = (2.f * m12 + C1) * (2.f * s12 + C2);
            const float den = (m1sq + m2sq + C1) * (s1 + s2 + C2);
            local += num * __builtin_amdgcn_rcpf(den);
        }
    }
}

__global__ __launch_bounds__(256)
__attribute__((amdgpu_waves_per_eu(2, 2)))   // budget 256 -> arch half ~128: ring fits ARCH
void ssim_stream(const float* __restrict__ X,
                 const float* __restrict__ Y,
                 float* __restrict__ planeSums) {
    constexpr float G[WIN] = GAUSS_INIT;
    const int tid = threadIdx.x;
    const int r0 = blockIdx.x * BH;
    const int c = (blockIdx.y << 8) + tid;    // this lane's single output col
    const int plane = blockIdx.z;
    const size_t pbase = (size_t)plane * IMG * IMG;
    const float* Xp = X + pbase;
    const float* Yp = Y + pbase;
    const int cbase = min(c & ~1, IMG - 12);  // aligned window base; clamp keeps
                                              // loads in-bounds, clamped lanes never emit

    // Per-lane 12-tap weights: even = {G,0}, odd = {0,G}. Named scalars (SSA).
    const bool odd = (c & 1) != 0;
    const float w0  = odd ? 0.f   : G[0];
    const float w1  = odd ? G[0]  : G[1];
    const float w2  = odd ? G[1]  : G[2];
    const float w3  = odd ? G[2]  : G[3];
    const float w4  = odd ? G[3]  : G[4];
    const float w5  = odd ? G[4]  : G[5];
    const float w6  = odd ? G[5]  : G[6];
    const float w7  = odd ? G[6]  : G[7];
    const float w8  = odd ? G[7]  : G[8];
    const float w9  = odd ? G[8]  : G[9];
    const float w10 = odd ? G[9]  : G[10];
    const float w11 = odd ? G[10] : 0.f;

    float a[5][WIN];                          // 55 regs; all accesses constexpr-indexed
    float local = 0.f;

    for (int base = 0; base < 44; base += WIN) {  // 4 x 11 phases, guard trims to 42
        phase_step<0>(base, r0, c, cbase, Xp, Yp, w0,w1,w2,w3,w4,w5,w6,w7,w8,w9,w10,w11, a, local);
        phase_step<1>(base, r0, c, cbase, Xp, Yp, w0,w1,w2,w3,w4,w5,w6,w7,w8,w9,w10,w11, a, local);
        phase_step<2>(base, r0, c, cbase, Xp, Yp, w0,w1,w2,w3,w4,w5,w6,w7,w8,w9,w10,w11, a, local);
        phase_step<3>(base, r0, c, cbase, Xp, Yp, w0,w1,w2,w3,w4,w5,w6,w7,w8,w9,w10,w11, a, local);
        phase_step<4>(base, r0, c, cbase, Xp, Yp, w0,w1,w2,w3,w4,w5,w6,w7,w8,w9,w10,w11, a, local);
        phase_step<5>(base, r0, c, cbase, Xp, Yp, w0,w1,w2,w3,w4,w5,w6,w7,w8,w9,w10,w11, a, local);
        phase_step<6>(base, r0, c, cbase, Xp, Yp, w0,w1,w2,w3,w4,w5,w6,w7,w8,w9,w10,w11, a, local);
        phase_step<7>(base, r0, c, cbase, Xp, Yp, w0,w1,w2,w3,w4,w5,w6,w7,w8,w9,w10,w11, a, local);
        phase_step<8>(base, r0, c, cbase, Xp, Yp, w0,w1,w2,w3,w4,w5,w6,w7,w8,w9,w10,w11, a, local);
        phase_step<9>(base, r0, c, cbase, Xp, Yp, w0,w1,w2,w3,w4,w5,w6,w7,w8,w9,w10,w11, a, local);
        phase_step<10>(base, r0, c, cbase, Xp, Yp, w0,w1,w2,w3,w4,w5,w6,w7,w8,w9,w10,w11, a, local);
    }

    // Block reduction -> one atomic per block (32 blocks/plane).
    #pragma unroll
    for (int off = 32; off > 0; off >>= 1)
        local += __shfl_down(local, off, 64);
    __shared__ float red[4];
    if ((tid & 63) == 0) red[tid >> 6] = local;
    __syncthreads();
    if (tid == 0)
        atomicAdd(&planeSums[plane], (red[0] + red[1]) + (red[2] + red[3]));
}

__global__ __launch_bounds__(128) void ssim_finalize(const float* __restrict__ planeSums,
                                                     float* __restrict__ out) {
    const int tid = threadIdx.x;
    float v = 0.f;
    if (tid < NPLANES) {
        const float m = planeSums[tid] * (1.0f / (float)(OUT_DIM * OUT_DIM));
        v = fmaxf(m, 0.f);   // nonnegative_ssim relu
    }
    #pragma unroll
    for (int off = 32; off > 0; off >>= 1)
        v += __shfl_down(v, off, 64);
    __shared__ float red[2];
    if ((tid & 63) == 0) red[tid >> 6] = v;
    __syncthreads();
    if (tid == 0) out[0] = 1.0f - (red[0] + red[1]) * (1.0f / (float)NPLANES);
}

extern "C" void kernel_launch(void* const* d_in, const int* in_sizes, int n_in,
                              void* d_out, int out_size, void* d_ws, size_t ws_size,
                              hipStream_t stream) {
    const float* X = (const float*)d_in[0];   // predictions
    const float* Y = (const float*)d_in[1];   // labels
    float* out = (float*)d_out;
    float* ws  = (float*)d_ws;                // 96 per-plane sums

    hipMemsetAsync(ws, 0, NPLANES * sizeof(float), stream);

    dim3 grid((OUT_DIM + BH - 1) / BH, 2, NPLANES);   // 16 x 2 x 96 = 3072 blocks
    ssim_stream<<<grid, 256, 0, stream>>>(X, Y, ws);
    ssim_finalize<<<1, 128, 0, stream>>>(ws, out);
}

// Round 7
// 331.781 us; speedup vs baseline: 1.1315x; 1.1315x over previous
//
#include <hip/hip_runtime.h>

// SSIM loss, streaming-row kernel, no LDS in the hot loop, no barriers.
// r5-r9: source rewrites at min-4-waves budget (128) -> allocator split
// 64 arch + AGPR/scratch spill (WRITE 28MB), dur 203us @ 4 waves/EU.
// r10: waves_per_eu(2,2) -> budget 256 -> CLEAN (VGPR=88, WRITE 96KB)
// but max=2 is a hard occupancy CAP -> 2 waves/EU, dur 259us.
// Key measurement: VALU-issue time is ~130us in BOTH (203x0.65 = 259x0.50)
// -> spill never doubled VALU; 4-waves-vs-2 latency hiding was the whole
// difference. The unsampled regime is {clean code, 4 waves}: clean demand
// is 88 regs <= 128, so 4 waves/EU is register-feasible with r10's exact
// code — only the attribute max forbids it.
// r11: waves_per_eu(2,4). Budget still from min=2 (256, no spill pressure);
// max=4 lifts the cap -> 4 waves/EU, 4 blocks/CU, 3 packed rounds.
// Algorithm unchanged (absmax 0.0 r5-r10): per-lane 12-tap parity-shifted
// Gaussian (zero pad tap, fmaf(0,x,h)==h bit-exact), aligned float2 loads
// consumed immediately, 11-slot rolling vertical accumulators.

#define IMG 512
#define OUT_DIM 502    // 512 - 10 (VALID conv twice)
#define WIN 11
#define BH 32          // output rows per band
#define NPHASE (BH + WIN - 1)   // 42
#define NPLANES 96

#define GAUSS_INIT {0.00102838f, 0.00759875f, 0.03600077f, 0.10936071f, \
                    0.21300553f, 0.26601172f, 0.21300553f, 0.10936071f, \
                    0.03600077f, 0.00759875f, 0.00102838f}

template<int PH>
__device__ __forceinline__ void phase_step(
    int base, int r0, int c, int cbase,
    const float* __restrict__ Xp, const float* __restrict__ Yp,
    float w0, float w1, float w2, float w3, float w4, float w5,
    float w6, float w7, float w8, float w9, float w10, float w11,
    float (&a)[5][WIN], float& local) {
    constexpr float G[WIN] = GAUSS_INIT;   // matches numpy fp32 (absmax 0.0)
    const int p = base + PH;
    if (p >= NPHASE) return;               // uniform; only last outer iter
    const int rr = min(r0 + p, IMG - 1);   // clamped rows feed only discarded outputs
    const float* px = Xp + rr * IMG + cbase;
    const float* py = Yp + rr * IMG + cbase;

    // Horizontal blur, 12 taps, parity-shifted weights. Each float2 pair is
    // consumed immediately after its load so the raw values die fast; tap
    // order stays ascending-k with 5 maps per tap -> bit-identical results.
    float h0 = 0.f, h1 = 0.f, h2 = 0.f, h3 = 0.f, h4 = 0.f;
#define PAIR(i, ka, kb) do {                                      \
        const float2 xv = *(const float2*)(px + 2 * (i));         \
        const float2 yv = *(const float2*)(py + 2 * (i));         \
        h0 = fmaf(w##ka, xv.x, h0);                               \
        h1 = fmaf(w##ka, yv.x, h1);                               \
        h2 = fmaf(w##ka, xv.x * xv.x, h2);                        \
        h3 = fmaf(w##ka, yv.x * yv.x, h3);                        \
        h4 = fmaf(w##ka, xv.x * yv.x, h4);                        \
        h0 = fmaf(w##kb, xv.y, h0);                               \
        h1 = fmaf(w##kb, yv.y, h1);                               \
        h2 = fmaf(w##kb, xv.y * xv.y, h2);                        \
        h3 = fmaf(w##kb, yv.y * yv.y, h3);                        \
        h4 = fmaf(w##kb, xv.y * yv.y, h4);                        \
    } while (0)
    PAIR(0, 0, 1); PAIR(1, 2, 3); PAIR(2, 4, 5);
    PAIR(3, 6, 7); PAIR(4, 8, 9); PAIR(5, 10, 11);
#undef PAIR

    // Row r contributes weight G[d] to output row r-d; slot (p-d) mod 11.
    // d==0 ASSIGNS its slot (freed by last phase's emit) -> no init/reset.
    // Every index is a true constexpr (template PH + literal d).
#define ACC(d) do {                                               \
        constexpr int s = (PH - (d) + 2 * WIN) % WIN;             \
        constexpr float g = G[(d)];                               \
        if ((d) == 0) {                                           \
            a[0][s] = g * h0; a[1][s] = g * h1; a[2][s] = g * h2; \
            a[3][s] = g * h3; a[4][s] = g * h4;                   \
        } else {                                                  \
            a[0][s] = fmaf(g, h0, a[0][s]);                       \
            a[1][s] = fmaf(g, h1, a[1][s]);                       \
            a[2][s] = fmaf(g, h2, a[2][s]);                       \
            a[3][s] = fmaf(g, h3, a[3][s]);                       \
            a[4][s] = fmaf(g, h4, a[4][s]);                       \
        }                                                         \
    } while (0)
    ACC(0); ACC(1); ACC(2); ACC(3); ACC(4); ACC(5);
    ACC(6); ACC(7); ACC(8); ACC(9); ACC(10);
#undef ACC

    // Output row o = r-10 completed this phase; its slot is (PH+1)%11.
    if (p >= WIN - 1) {
        const int o = r0 + p - (WIN - 1);
        if (o < OUT_DIM && c < OUT_DIM) {
            constexpr int se = (PH + 1) % WIN;
            const float C1 = 0.0001f, C2 = 0.0009f;
            const float m1 = a[0][se], m2 = a[1][se];
            const float m1sq = m1 * m1, m2sq = m2 * m2, m12 = m1 * m2;
            const float s1  = a[2][se] - m1sq;
            const float s2  = a[3][se] - m2sq;
            const float s12 = a[4][se] - m12;
            const float num = (2.f * m12 + C1) * (2.f * s12 + C2);
            const float den = (m1sq + m2sq + C1) * (s1 + s2 + C2);
            local += num * __builtin_amdgcn_rcpf(den);
        }
    }
}

__global__ __launch_bounds__(256)
__attribute__((amdgpu_waves_per_eu(2, 4)))   // budget from min=2 (no spill); max=4 lifts cap
void ssim_stream(const float* __restrict__ X,
                 const float* __restrict__ Y,
                 float* __restrict__ planeSums) {
    constexpr float G[WIN] = GAUSS_INIT;
    const int tid = threadIdx.x;
    const int r0 = blockIdx.x * BH;
    const int c = (blockIdx.y << 8) + tid;    // this lane's single output col
    const int plane = blockIdx.z;
    const size_t pbase = (size_t)plane * IMG * IMG;
    const float* Xp = X + pbase;
    const float* Yp = Y + pbase;
    const int cbase = min(c & ~1, IMG - 12);  // aligned window base; clamp keeps
                                              // loads in-bounds, clamped lanes never emit

    // Per-lane 12-tap weights: even = {G,0}, odd = {0,G}. Named scalars (SSA).
    const bool odd = (c & 1) != 0;
    const float w0  = odd ? 0.f   : G[0];
    const float w1  = odd ? G[0]  : G[1];
    const float w2  = odd ? G[1]  : G[2];
    const float w3  = odd ? G[2]  : G[3];
    const float w4  = odd ? G[3]  : G[4];
    const float w5  = odd ? G[4]  : G[5];
    const float w6  = odd ? G[5]  : G[6];
    const float w7  = odd ? G[6]  : G[7];
    const float w8  = odd ? G[7]  : G[8];
    const float w9  = odd ? G[8]  : G[9];
    const float w10 = odd ? G[9]  : G[10];
    const float w11 = odd ? G[10] : 0.f;

    float a[5][WIN];                          // 55 regs; all accesses constexpr-indexed
    float local = 0.f;

    for (int base = 0; base < 44; base += WIN) {  // 4 x 11 phases, guard trims to 42
        phase_step<0>(base, r0, c, cbase, Xp, Yp, w0,w1,w2,w3,w4,w5,w6,w7,w8,w9,w10,w11, a, local);
        phase_step<1>(base, r0, c, cbase, Xp, Yp, w0,w1,w2,w3,w4,w5,w6,w7,w8,w9,w10,w11, a, local);
        phase_step<2>(base, r0, c, cbase, Xp, Yp, w0,w1,w2,w3,w4,w5,w6,w7,w8,w9,w10,w11, a, local);
        phase_step<3>(base, r0, c, cbase, Xp, Yp, w0,w1,w2,w3,w4,w5,w6,w7,w8,w9,w10,w11, a, local);
        phase_step<4>(base, r0, c, cbase, Xp, Yp, w0,w1,w2,w3,w4,w5,w6,w7,w8,w9,w10,w11, a, local);
        phase_step<5>(base, r0, c, cbase, Xp, Yp, w0,w1,w2,w3,w4,w5,w6,w7,w8,w9,w10,w11, a, local);
        phase_step<6>(base, r0, c, cbase, Xp, Yp, w0,w1,w2,w3,w4,w5,w6,w7,w8,w9,w10,w11, a, local);
        phase_step<7>(base, r0, c, cbase, Xp, Yp, w0,w1,w2,w3,w4,w5,w6,w7,w8,w9,w10,w11, a, local);
        phase_step<8>(base, r0, c, cbase, Xp, Yp, w0,w1,w2,w3,w4,w5,w6,w7,w8,w9,w10,w11, a, local);
        phase_step<9>(base, r0, c, cbase, Xp, Yp, w0,w1,w2,w3,w4,w5,w6,w7,w8,w9,w10,w11, a, local);
        phase_step<10>(base, r0, c, cbase, Xp, Yp, w0,w1,w2,w3,w4,w5,w6,w7,w8,w9,w10,w11, a, local);
    }

    // Block reduction -> one atomic per block (32 blocks/plane).
    #pragma unroll
    for (int off = 32; off > 0; off >>= 1)
        local += __shfl_down(local, off, 64);
    __shared__ float red[4];
    if ((tid & 63) == 0) red[tid >> 6] = local;
    __syncthreads();
    if (tid == 0)
        atomicAdd(&planeSums[plane], (red[0] + red[1]) + (red[2] + red[3]));
}

__global__ __launch_bounds__(128) void ssim_finalize(const float* __restrict__ planeSums,
                                                     float* __restrict__ out) {
    const int tid = threadIdx.x;
    float v = 0.f;
    if (tid < NPLANES) {
        const float m = planeSums[tid] * (1.0f / (float)(OUT_DIM * OUT_DIM));
        v = fmaxf(m, 0.f);   // nonnegative_ssim relu
    }
    #pragma unroll
    for (int off = 32; off > 0; off >>= 1)
        v += __shfl_down(v, off, 64);
    __shared__ float red[2];
    if ((tid & 63) == 0) red[tid >> 6] = v;
    __syncthreads();
    if (tid == 0) out[0] = 1.0f - (red[0] + red[1]) * (1.0f / (float)NPLANES);
}

extern "C" void kernel_launch(void* const* d_in, const int* in_sizes, int n_in,
                              void* d_out, int out_size, void* d_ws, size_t ws_size,
                              hipStream_t stream) {
    const float* X = (const float*)d_in[0];   // predictions
    const float* Y = (const float*)d_in[1];   // labels
    float* out = (float*)d_out;
    float* ws  = (float*)d_ws;                // 96 per-plane sums

    hipMemsetAsync(ws, 0, NPLANES * sizeof(float), stream);

    dim3 grid((OUT_DIM + BH - 1) / BH, 2, NPLANES);   // 16 x 2 x 96 = 3072 blocks
    ssim_stream<<<grid, 256, 0, stream>>>(X, Y, ws);
    ssim_finalize<<<1, 128, 0, stream>>>(ws, out);
}